// Round 5
// baseline (650.382 us; speedup 1.0000x reference)
//
#include <hip/hip_runtime.h>

typedef unsigned short u16;
typedef unsigned int u32;
typedef short s8v __attribute__((ext_vector_type(8)));   // 8 bf16 in 4 VGPRs
typedef float f4  __attribute__((ext_vector_type(4)));   // MFMA acc

constexpr int ND = 512, NL = 3, NK = 256;
constexpr int ROWS = 128 * 1024;
#define TM 32
#define DELTA 0.75f

// ---- workspace layout ----
constexpr int CSQ_OFF = 0;                    // 768 floats
constexpr int G01_OFF = 1024;
constexpr int G02_OFF = G01_OFF + 65536;
constexpr int G12_OFF = G02_OFF + 65536;
constexpr int WS_FLOATS = G12_OFF + 65536;    // 197632 floats
// bf16 fragment table: [kt=16][48 tiles][512 ushorts], tile position within a
// kt-slab = (ct_g&3)*12 + (ct_g>>2)  (so wave wc's 12 tiles are contiguous)
constexpr int BGH_OFF_US = WS_FLOATS * 2;     // ushort offset
// total bytes = 197632*4 + 768*512*2 = 1.58 MB

__device__ __forceinline__ u16 f2bf(float f) {          // fp32 -> bf16 RNE
    unsigned u = __float_as_uint(f);
    return (u16)((u + 0x7fffu + ((u >> 16) & 1u)) >> 16);
}

// ---------------------------------------------------------------------------
__global__ __launch_bounds__(256) void prep_csq(const float* __restrict__ C,
                                                float* __restrict__ ws) {
    int wid  = blockIdx.x * 4 + (threadIdx.x >> 6);   // 0..767
    int lane = threadIdx.x & 63;
    const float4* src = reinterpret_cast<const float4*>(C + (size_t)wid * ND + lane * 8);
    float4 a = src[0], b = src[1];
    float sq = a.x*a.x + a.y*a.y + a.z*a.z + a.w*a.w
             + b.x*b.x + b.y*b.y + b.z*b.z + b.w*b.w;
    #pragma unroll
    for (int m = 1; m < 64; m <<= 1) sq += __shfl_xor(sq, m, 64);
    if (lane == 0) ws[CSQ_OFF + wid] = sq;
}

// ---------------------------------------------------------------------------
// B fragment table, wave-contiguous order.
// wid = l*256 + kt*16 + ct; ct_g = l*16+ct; pos = (ct_g&3)*12 + (ct_g>>2)
// lane slot: col = ct*16 + (lane&15), k = kt*32 + (lane>>4)*8 + j (j=0..7)
__global__ __launch_bounds__(256) void prep_b(const float* __restrict__ C,
                                              u16* __restrict__ wsu) {
    int wid  = blockIdx.x * 4 + (threadIdx.x >> 6);   // 0..767
    int lane = threadIdx.x & 63;
    int l  = wid >> 8, kt = (wid >> 4) & 15, ct = wid & 15;
    int n  = ct * 16 + (lane & 15);
    int k0 = kt * 32 + (lane >> 4) * 8;
    const float* src = C + ((size_t)l * NK + n) * ND + k0;
    float4 xa = *reinterpret_cast<const float4*>(src);
    float4 xb = *reinterpret_cast<const float4*>(src + 4);
    float x[8] = {xa.x, xa.y, xa.z, xa.w, xb.x, xb.y, xb.z, xb.w};
    unsigned hp[4];
    #pragma unroll
    for (int q = 0; q < 4; ++q) {
        u16 h0 = f2bf(x[2*q]), h1 = f2bf(x[2*q+1]);
        hp[q] = (unsigned)h0 | ((unsigned)h1 << 16);
    }
    uint4 hv = {hp[0], hp[1], hp[2], hp[3]};
    int ct_g = l * 16 + ct;
    int pos  = (ct_g & 3) * 12 + (ct_g >> 2);
    int TI   = kt * 48 + pos;
    *reinterpret_cast<uint4*>(wsu + BGH_OFF_US + (size_t)TI * 512 + lane * 8) = hv;
}

// ---------------------------------------------------------------------------
__global__ __launch_bounds__(256) void gram_kernel(const float* __restrict__ C,
                                                   float* __restrict__ ws) {
    int p = blockIdx.x >> 8;       // 0:(0,1) 1:(0,2) 2:(1,2)
    int i = blockIdx.x & 255;
    int a = (p == 2) ? 1 : 0;
    int b = (p == 0) ? 1 : 2;
    __shared__ float Ca[512];
    float2 v = *reinterpret_cast<const float2*>(C + ((size_t)a * NK + i) * ND + threadIdx.x * 2);
    Ca[threadIdx.x * 2]     = v.x;
    Ca[threadIdx.x * 2 + 1] = v.y;
    __syncthreads();
    int j = threadIdx.x;
    const float* Cb = C + ((size_t)b * NK + j) * ND;
    float s = 0.f;
    for (int d = 0; d < 512; d += 8) {
        float4 u = *reinterpret_cast<const float4*>(Cb + d);
        float4 w = *reinterpret_cast<const float4*>(Cb + d + 4);
        s = fmaf(u.x, Ca[d+0], s); s = fmaf(u.y, Ca[d+1], s);
        s = fmaf(u.z, Ca[d+2], s); s = fmaf(u.w, Ca[d+3], s);
        s = fmaf(w.x, Ca[d+4], s); s = fmaf(w.y, Ca[d+5], s);
        s = fmaf(w.z, Ca[d+6], s); s = fmaf(w.w, Ca[d+7], s);
    }
    float* G = ws + ((p == 0) ? G01_OFF : (p == 1) ? G02_OFF : G12_OFF);
    G[(size_t)i * NK + j] = s;
}

// ---------------------------------------------------------------------------
// Main: 32 rows x 768 cols per block; 512 threads = 8 waves = 2 wr x 4 wc.
// Wave: rows wr*16..+15, col-tiles ct_g = wc + 4f (f=0..11), acc = 12 f4.
// Barrier-free GEMM: A converted in-reg from global (2-kt prefetch), B from
// L2-resident fragment table (wave-contiguous 12KB per kt).
__global__ __launch_bounds__(512, 4) void rq_fused(const float* __restrict__ X,
                                                   const float* __restrict__ C,
                                                   const float* __restrict__ ws,
                                                   const u16* __restrict__ wsu,
                                                   float* __restrict__ out) {
    __shared__ float redV[4][32];
    __shared__ int   redI[4][32];
    __shared__ float mrow[32];
    __shared__ int   iseltmp[32];
    __shared__ int   isel[3][32];
    __shared__ int   ccnt[32];
    __shared__ int   ntask;
    __shared__ int   taskRC[256];
    __shared__ float taskS[256];

    const int tid  = threadIdx.x;
    const int w    = tid >> 6;          // 0..7
    const int lane = tid & 63;
    const int wr   = w >> 2;            // 0..1
    const int wc   = w & 3;             // 0..3
    const int hi4  = lane >> 4, l15 = lane & 15;
    const int row0 = blockIdx.x * TM;

    const float* csq = ws + CSQ_OFF;
    const float* G01 = ws + G01_OFF;
    const float* G02 = ws + G02_OFF;
    const float* G12 = ws + G12_OFF;

    f4 acc[12];
    #pragma unroll
    for (int f = 0; f < 12; ++f) acc[f] = (f4){0.f, 0.f, 0.f, 0.f};

    // ---- barrier-free main loop ----
    const float* xrow = X + (size_t)(row0 + wr * 16 + l15) * ND + hi4 * 8;
    const u16*  bbase = wsu + BGH_OFF_US + (size_t)wc * 12 * 512 + lane * 8;

    float4 xa0 = *reinterpret_cast<const float4*>(xrow);
    float4 xb0 = *reinterpret_cast<const float4*>(xrow + 4);
    float4 xa1 = *reinterpret_cast<const float4*>(xrow + 32);
    float4 xb1 = *reinterpret_cast<const float4*>(xrow + 36);

    #pragma unroll 2
    for (int kt = 0; kt < 16; ++kt) {
        s8v a;
        a[0] = (short)f2bf(xa0.x); a[1] = (short)f2bf(xa0.y);
        a[2] = (short)f2bf(xa0.z); a[3] = (short)f2bf(xa0.w);
        a[4] = (short)f2bf(xb0.x); a[5] = (short)f2bf(xb0.y);
        a[6] = (short)f2bf(xb0.z); a[7] = (short)f2bf(xb0.w);
        xa0 = xa1; xb0 = xb1;
        if (kt + 2 < 16) {
            xa1 = *reinterpret_cast<const float4*>(xrow + (kt + 2) * 32);
            xb1 = *reinterpret_cast<const float4*>(xrow + (kt + 2) * 32 + 4);
        }
        const u16* bp = bbase + (size_t)kt * (48 * 512);
        #pragma unroll
        for (int f = 0; f < 12; ++f) {
            s8v b = *reinterpret_cast<const s8v*>(bp + f * 512);
            acc[f] = __builtin_amdgcn_mfma_f32_16x16x32_bf16(a, b, acc[f], 0, 0, 0);
        }
    }

    // ---- cascade: per-layer score transform + argmin + exact refine ----
    #pragma unroll
    for (int l = 0; l < NL; ++l) {
        if (tid < 32) ccnt[tid] = 0;
        if (tid == 0) ntask = 0;

        float bv[4]; int bi[4];
        #pragma unroll
        for (int reg = 0; reg < 4; ++reg) { bv[reg] = 3.4e38f; bi[reg] = 0x7fffffff; }

        #pragma unroll
        for (int e = 0; e < 4; ++e) {
            const int f  = 4 * l + e;
            const int lc = (wc + 4 * e) * 16 + l15;     // col within layer
            const int gc = l * 256 + lc;                // global col
            const float cs = csq[gc];
            #pragma unroll
            for (int reg = 0; reg < 4; ++reg) {
                const int row = wr * 16 + hi4 * 4 + reg;
                float s = cs - 2.f * acc[f][reg];
                if (l == 1) s += 2.f * G01[(size_t)isel[0][row] * NK + lc];
                if (l == 2) s += 2.f * (G02[(size_t)isel[0][row] * NK + lc] +
                                        G12[(size_t)isel[1][row] * NK + lc]);
                acc[f][reg] = s;
                if (s < bv[reg] || (s == bv[reg] && gc < bi[reg])) {
                    bv[reg] = s; bi[reg] = gc;
                }
            }
        }
        #pragma unroll
        for (int reg = 0; reg < 4; ++reg) {
            float v = bv[reg]; int ix = bi[reg];
            #pragma unroll
            for (int m = 1; m < 16; m <<= 1) {
                float v2 = __shfl_xor(v, m, 64);
                int   i2 = __shfl_xor(ix, m, 64);
                if (v2 < v || (v2 == v && i2 < ix)) { v = v2; ix = i2; }
            }
            if (l15 == 0) {
                int row = wr * 16 + hi4 * 4 + reg;
                redV[wc][row] = v; redI[wc][row] = ix;
            }
        }
        __syncthreads();
        if (tid < 32) {
            float v = redV[0][tid]; int ix = redI[0][tid];
            #pragma unroll
            for (int q = 1; q < 4; ++q) {
                float v2 = redV[q][tid]; int i2 = redI[q][tid];
                if (v2 < v || (v2 == v && i2 < ix)) { v = v2; ix = i2; }
            }
            mrow[tid] = v; iseltmp[tid] = ix;
        }
        __syncthreads();
        // pass 1: count near-ties per row
        #pragma unroll
        for (int e = 0; e < 4; ++e) {
            const int f = 4 * l + e;
            #pragma unroll
            for (int reg = 0; reg < 4; ++reg) {
                const int row = wr * 16 + hi4 * 4 + reg;
                if (acc[f][reg] <= mrow[row] + DELTA)
                    atomicAdd(&ccnt[row], 1);
            }
        }
        __syncthreads();
        // pass 2: append candidates for contested rows
        #pragma unroll
        for (int e = 0; e < 4; ++e) {
            const int f  = 4 * l + e;
            const int lc = (wc + 4 * e) * 16 + l15;
            const int gc = l * 256 + lc;
            #pragma unroll
            for (int reg = 0; reg < 4; ++reg) {
                const int row = wr * 16 + hi4 * 4 + reg;
                if (ccnt[row] >= 2 && acc[f][reg] <= mrow[row] + DELTA) {
                    int t = atomicAdd(&ntask, 1);
                    if (t < 256) taskRC[t] = (row << 10) | gc;
                }
            }
        }
        __syncthreads();
        // exact fp32 rescore (one wave per task)
        {
            int nt = ntask < 256 ? ntask : 256;
            for (int ti = w; ti < nt; ti += 8) {
                int rc = taskRC[ti];
                int trow = rc >> 10, gcol = rc & 1023;
                const float* xr = X + (size_t)(row0 + trow) * ND + lane * 8;
                const float* cr = C + (size_t)gcol * ND + lane * 8;
                float4 xa = *reinterpret_cast<const float4*>(xr);
                float4 xb = *reinterpret_cast<const float4*>(xr + 4);
                float4 ca = *reinterpret_cast<const float4*>(cr);
                float4 cb = *reinterpret_cast<const float4*>(cr + 4);
                float d = xa.x*ca.x + xa.y*ca.y + xa.z*ca.z + xa.w*ca.w
                        + xb.x*cb.x + xb.y*cb.y + xb.z*cb.z + xb.w*cb.w;
                #pragma unroll
                for (int m = 1; m < 64; m <<= 1) d += __shfl_xor(d, m, 64);
                if (lane == 0) {
                    int lc2 = gcol & 255;
                    float sc = csq[gcol] - 2.f * d;
                    if (l == 1) sc += 2.f * G01[(size_t)isel[0][trow] * NK + lc2];
                    if (l == 2) sc += 2.f * (G02[(size_t)isel[0][trow] * NK + lc2] +
                                             G12[(size_t)isel[1][trow] * NK + lc2]);
                    taskS[ti] = sc;
                }
            }
        }
        __syncthreads();
        if (tid < 32) {
            int best = iseltmp[tid];
            if (ccnt[tid] >= 2) {
                float bvv = 3.4e38f; int bii = 0x7fffffff;
                int nt = ntask < 256 ? ntask : 256;
                for (int t = 0; t < nt; ++t) {
                    int rc = taskRC[t];
                    if ((rc >> 10) == tid) {
                        float s = taskS[t]; int c = rc & 1023;
                        if (s < bvv || (s == bvv && c < bii)) { bvv = s; bii = c; }
                    }
                }
                best = bii;
            }
            isel[l][tid] = best & 255;
        }
        __syncthreads();
    }

    // ---- outputs ----
    if (tid < TM * 3) {
        int r = tid / 3, l = tid % 3;
        out[(size_t)(row0 + r) * 3 + l] = (float)isel[l][r];
    }
    float* rec = out + (size_t)ROWS * 3;
    #pragma unroll
    for (int q = 0; q < 8; ++q) {
        int idx = tid + 512 * q;          // 0..4095
        int r   = idx >> 7;               // 0..31
        int d4  = (idx & 127) * 4;
        float4 v0 = *reinterpret_cast<const float4*>(C + ((size_t)(  0 + isel[0][r])) * ND + d4);
        float4 v1 = *reinterpret_cast<const float4*>(C + ((size_t)(256 + isel[1][r])) * ND + d4);
        float4 v2 = *reinterpret_cast<const float4*>(C + ((size_t)(512 + isel[2][r])) * ND + d4);
        float4 o;
        o.x = v0.x + v1.x + v2.x;
        o.y = v0.y + v1.y + v2.y;
        o.z = v0.z + v1.z + v2.z;
        o.w = v0.w + v1.w + v2.w;
        *reinterpret_cast<float4*>(rec + (size_t)(row0 + r) * ND + d4) = o;
    }
}

// ---------------------------------------------------------------------------
extern "C" void kernel_launch(void* const* d_in, const int* in_sizes, int n_in,
                              void* d_out, int out_size, void* d_ws, size_t ws_size,
                              hipStream_t stream) {
    const float* X  = (const float*)d_in[0];   // [128,1024,512]
    const float* C  = (const float*)d_in[1];   // [3,256,512]
    float* ws  = (float*)d_ws;
    u16*   wsu = (u16*)d_ws;
    float* out = (float*)d_out;

    hipLaunchKernelGGL(prep_csq,    dim3(192),       dim3(256), 0, stream, C, ws);
    hipLaunchKernelGGL(prep_b,      dim3(192),       dim3(256), 0, stream, C, wsu);
    hipLaunchKernelGGL(gram_kernel, dim3(768),       dim3(256), 0, stream, C, ws);
    hipLaunchKernelGGL(rq_fused,    dim3(ROWS / TM), dim3(512), 0, stream,
                       X, C, ws, wsu, out);
}

// Round 6
// 405.822 us; speedup vs baseline: 1.6026x; 1.6026x over previous
//
#include <hip/hip_runtime.h>

typedef unsigned short u16;
typedef unsigned int u32;
typedef short s8v __attribute__((ext_vector_type(8)));   // 8 bf16 in 4 VGPRs
typedef float f4  __attribute__((ext_vector_type(4)));   // MFMA acc

constexpr int ND = 512, NL = 3, NK = 256;
constexpr int ROWS = 128 * 1024;
#define TM 32
#define DELTA 0.75f

// ---- workspace layout ----
constexpr int CSQ_OFF = 0;                    // 768 floats
constexpr int G01_OFF = 1024;
constexpr int G02_OFF = G01_OFF + 65536;
constexpr int G12_OFF = G02_OFF + 65536;
constexpr int WS_FLOATS = G12_OFF + 65536;    // 197632 floats
// bf16 fragment table, TILE-MAJOR: [tile_g=48][kt=16][512 u16]
// tile_g = l*16 + ct ; within tile, kt slabs contiguous (16 KB per tile)
constexpr int BT_OFF_US = WS_FLOATS * 2;      // ushort offset

__device__ __forceinline__ u16 f2bf(float f) {          // fp32 -> bf16 RNE
    unsigned u = __float_as_uint(f);
    return (u16)((u + 0x7fffu + ((u >> 16) & 1u)) >> 16);
}

// ---------------------------------------------------------------------------
__global__ __launch_bounds__(256) void prep_csq(const float* __restrict__ C,
                                                float* __restrict__ ws) {
    int wid  = blockIdx.x * 4 + (threadIdx.x >> 6);   // 0..767
    int lane = threadIdx.x & 63;
    const float4* src = reinterpret_cast<const float4*>(C + (size_t)wid * ND + lane * 8);
    float4 a = src[0], b = src[1];
    float sq = a.x*a.x + a.y*a.y + a.z*a.z + a.w*a.w
             + b.x*b.x + b.y*b.y + b.z*b.z + b.w*b.w;
    #pragma unroll
    for (int m = 1; m < 64; m <<= 1) sq += __shfl_xor(sq, m, 64);
    if (lane == 0) ws[CSQ_OFF + wid] = sq;
}

// ---------------------------------------------------------------------------
// B fragment table, tile-major. wid = l*256 + kt*16 + ct.
// lane slot: col = ct*16 + (lane&15), k = kt*32 + (lane>>4)*8 + j (j=0..7)
__global__ __launch_bounds__(256) void prep_b(const float* __restrict__ C,
                                              u16* __restrict__ wsu) {
    int wid  = blockIdx.x * 4 + (threadIdx.x >> 6);   // 0..767
    int lane = threadIdx.x & 63;
    int l  = wid >> 8, kt = (wid >> 4) & 15, ct = wid & 15;
    int n  = ct * 16 + (lane & 15);
    int k0 = kt * 32 + (lane >> 4) * 8;
    const float* src = C + ((size_t)l * NK + n) * ND + k0;
    float4 xa = *reinterpret_cast<const float4*>(src);
    float4 xb = *reinterpret_cast<const float4*>(src + 4);
    float x[8] = {xa.x, xa.y, xa.z, xa.w, xb.x, xb.y, xb.z, xb.w};
    unsigned hp[4];
    #pragma unroll
    for (int q = 0; q < 4; ++q) {
        u16 h0 = f2bf(x[2*q]), h1 = f2bf(x[2*q+1]);
        hp[q] = (unsigned)h0 | ((unsigned)h1 << 16);
    }
    uint4 hv = {hp[0], hp[1], hp[2], hp[3]};
    int tile_g = l * 16 + ct;
    int TI     = tile_g * 16 + kt;
    *reinterpret_cast<uint4*>(wsu + BT_OFF_US + (size_t)TI * 512 + lane * 8) = hv;
}

// ---------------------------------------------------------------------------
__global__ __launch_bounds__(256) void gram_kernel(const float* __restrict__ C,
                                                   float* __restrict__ ws) {
    int p = blockIdx.x >> 8;       // 0:(0,1) 1:(0,2) 2:(1,2)
    int i = blockIdx.x & 255;
    int a = (p == 2) ? 1 : 0;
    int b = (p == 0) ? 1 : 2;
    __shared__ float Ca[512];
    float2 v = *reinterpret_cast<const float2*>(C + ((size_t)a * NK + i) * ND + threadIdx.x * 2);
    Ca[threadIdx.x * 2]     = v.x;
    Ca[threadIdx.x * 2 + 1] = v.y;
    __syncthreads();
    int j = threadIdx.x;
    const float* Cb = C + ((size_t)b * NK + j) * ND;
    float s = 0.f;
    for (int d = 0; d < 512; d += 8) {
        float4 u = *reinterpret_cast<const float4*>(Cb + d);
        float4 w = *reinterpret_cast<const float4*>(Cb + d + 4);
        s = fmaf(u.x, Ca[d+0], s); s = fmaf(u.y, Ca[d+1], s);
        s = fmaf(u.z, Ca[d+2], s); s = fmaf(u.w, Ca[d+3], s);
        s = fmaf(w.x, Ca[d+4], s); s = fmaf(w.y, Ca[d+5], s);
        s = fmaf(w.z, Ca[d+6], s); s = fmaf(w.w, Ca[d+7], s);
    }
    float* G = ws + ((p == 0) ? G01_OFF : (p == 1) ? G02_OFF : G12_OFF);
    G[(size_t)i * NK + j] = s;
}

// ---------------------------------------------------------------------------
// Main: 32 rows/block, 512 threads = 8 waves. Per layer, wave w computes
// col-tiles {w, w+8} for both 16-row tiles (acc = 4 f4 = 16 VGPR), then the
// layer's argmin+refine frees the scores before the next layer's GEMM.
// A-fragments converted ONCE into LDS (32 KB); B streamed tile-major from L2.
__global__ __launch_bounds__(512, 6) void rq_fused(const float* __restrict__ X,
                                                   const float* __restrict__ C,
                                                   const float* __restrict__ ws,
                                                   const u16* __restrict__ wsu,
                                                   float* __restrict__ out) {
    __shared__ __align__(16) u16 Af[2 * 16 * 512];   // 32 KB A-frags [rt][kt][512]
    __shared__ float redV[8][32];
    __shared__ int   redI[8][32];
    __shared__ float mrow[32];
    __shared__ int   iseltmp[32];
    __shared__ int   isel[3][32];
    __shared__ int   ccnt[32];
    __shared__ int   ntask;
    __shared__ int   taskRC[256];
    __shared__ float taskS[256];

    const int tid  = threadIdx.x;
    const int w    = tid >> 6;          // 0..7
    const int lane = tid & 63;
    const int hi4  = lane >> 4, l15 = lane & 15;
    const int row0 = blockIdx.x * TM;

    const float* csq = ws + CSQ_OFF;
    const float* G01 = ws + G01_OFF;
    const float* G02 = ws + G02_OFF;
    const float* G12 = ws + G12_OFF;
    const u16*   Bt  = wsu + BT_OFF_US;

    // ---- stage + convert X tile into A-fragment LDS (once) ----
    {
        const int srow  = tid >> 4;           // 0..31
        const int scol0 = (tid & 15) * 4;
        const float* xsrc = X + (size_t)(row0 + srow) * ND + scol0;
        #pragma unroll
        for (int p = 0; p < 8; ++p) {
            float4 v = *reinterpret_cast<const float4*>(xsrc + p * 64);
            int col = scol0 + p * 64;
            int kt = col >> 5, kk = col & 31;
            int idx = (srow >> 4) * 8192 + kt * 512
                    + ((srow & 15) + 16 * (kk >> 3)) * 8 + (kk & 7);
            u32 pk0 = (u32)f2bf(v.x) | ((u32)f2bf(v.y) << 16);
            u32 pk1 = (u32)f2bf(v.z) | ((u32)f2bf(v.w) << 16);
            *reinterpret_cast<uint2*>(&Af[idx]) = (uint2){pk0, pk1};
        }
    }
    __syncthreads();

    // ---- per-layer: GEMM (16 regs live) + argmin + exact refine ----
    #pragma unroll
    for (int l = 0; l < NL; ++l) {
        f4 acc00 = (f4){0.f,0.f,0.f,0.f}, acc01 = acc00;
        f4 acc10 = acc00, acc11 = acc00;

        const u16* bp0 = Bt + (size_t)((l * 16 + w) * 16) * 512 + lane * 8;
        const u16* bp1 = bp0 + (size_t)8 * 16 * 512;   // tile w+8
        const u16* ap  = Af + lane * 8;

        #pragma unroll
        for (int kt = 0; kt < 16; ++kt) {
            s8v b0 = *reinterpret_cast<const s8v*>(bp0 + kt * 512);
            s8v b1 = *reinterpret_cast<const s8v*>(bp1 + kt * 512);
            s8v a0 = *reinterpret_cast<const s8v*>(ap + kt * 512);
            s8v a1 = *reinterpret_cast<const s8v*>(ap + 8192 + kt * 512);
            acc00 = __builtin_amdgcn_mfma_f32_16x16x32_bf16(a0, b0, acc00, 0, 0, 0);
            acc10 = __builtin_amdgcn_mfma_f32_16x16x32_bf16(a1, b0, acc10, 0, 0, 0);
            acc01 = __builtin_amdgcn_mfma_f32_16x16x32_bf16(a0, b1, acc01, 0, 0, 0);
            acc11 = __builtin_amdgcn_mfma_f32_16x16x32_bf16(a1, b1, acc11, 0, 0, 0);
        }

        // scores in-place + per-lane best (cols lc0 = (w)*16+l15, lc1 = (w+8)*16+l15)
        f4 sc[2][2];
        sc[0][0] = acc00; sc[0][1] = acc01; sc[1][0] = acc10; sc[1][1] = acc11;

        float bv[2][4]; int bi[2][4];
        #pragma unroll
        for (int rt = 0; rt < 2; ++rt)
            #pragma unroll
            for (int reg = 0; reg < 4; ++reg) { bv[rt][reg] = 3.4e38f; bi[rt][reg] = 0x7fffffff; }

        #pragma unroll
        for (int e = 0; e < 2; ++e) {
            const int lc = (w + 8 * e) * 16 + l15;
            const int gc = l * 256 + lc;
            const float cs = csq[gc];
            #pragma unroll
            for (int rt = 0; rt < 2; ++rt)
                #pragma unroll
                for (int reg = 0; reg < 4; ++reg) {
                    const int row = rt * 16 + hi4 * 4 + reg;
                    float s = cs - 2.f * sc[rt][e][reg];
                    if (l == 1) s += 2.f * G01[(size_t)isel[0][row] * NK + lc];
                    if (l == 2) s += 2.f * (G02[(size_t)isel[0][row] * NK + lc] +
                                            G12[(size_t)isel[1][row] * NK + lc]);
                    sc[rt][e][reg] = s;
                    if (s < bv[rt][reg] || (s == bv[rt][reg] && gc < bi[rt][reg])) {
                        bv[rt][reg] = s; bi[rt][reg] = gc;
                    }
                }
        }
        #pragma unroll
        for (int rt = 0; rt < 2; ++rt)
            #pragma unroll
            for (int reg = 0; reg < 4; ++reg) {
                float v = bv[rt][reg]; int ix = bi[rt][reg];
                #pragma unroll
                for (int m = 1; m < 16; m <<= 1) {
                    float v2 = __shfl_xor(v, m, 64);
                    int   i2 = __shfl_xor(ix, m, 64);
                    if (v2 < v || (v2 == v && i2 < ix)) { v = v2; ix = i2; }
                }
                if (l15 == 0) {
                    int row = rt * 16 + hi4 * 4 + reg;
                    redV[w][row] = v; redI[w][row] = ix;
                }
            }
        if (tid < 32) ccnt[tid] = 0;
        if (tid == 0) ntask = 0;
        __syncthreads();                               // b1

        if (tid < 32) {
            float v = redV[0][tid]; int ix = redI[0][tid];
            #pragma unroll
            for (int q = 1; q < 8; ++q) {
                float v2 = redV[q][tid]; int i2 = redI[q][tid];
                if (v2 < v || (v2 == v && i2 < ix)) { v = v2; ix = i2; }
            }
            mrow[tid] = v; iseltmp[tid] = ix;
        }
        __syncthreads();                               // b2

        // single candidate pass: count + append
        #pragma unroll
        for (int e = 0; e < 2; ++e) {
            const int lc = (w + 8 * e) * 16 + l15;
            const int gc = l * 256 + lc;
            #pragma unroll
            for (int rt = 0; rt < 2; ++rt)
                #pragma unroll
                for (int reg = 0; reg < 4; ++reg) {
                    const int row = rt * 16 + hi4 * 4 + reg;
                    if (sc[rt][e][reg] <= mrow[row] + DELTA) {
                        atomicAdd(&ccnt[row], 1);
                        int t = atomicAdd(&ntask, 1);
                        if (t < 256) taskRC[t] = (row << 10) | gc;
                    }
                }
        }
        __syncthreads();                               // b3

        // exact fp32 rescore of contested rows (one wave per task)
        {
            int nt = ntask < 256 ? ntask : 256;
            for (int ti = w; ti < nt; ti += 8) {
                int rc = taskRC[ti];
                int trow = rc >> 10, gcol = rc & 1023;
                if (ccnt[trow] >= 2) {
                    const float* xr = X + (size_t)(row0 + trow) * ND + lane * 8;
                    const float* cr = C + (size_t)gcol * ND + lane * 8;
                    float4 xa = *reinterpret_cast<const float4*>(xr);
                    float4 xb = *reinterpret_cast<const float4*>(xr + 4);
                    float4 ca = *reinterpret_cast<const float4*>(cr);
                    float4 cb = *reinterpret_cast<const float4*>(cr + 4);
                    float d = xa.x*ca.x + xa.y*ca.y + xa.z*ca.z + xa.w*ca.w
                            + xb.x*cb.x + xb.y*cb.y + xb.z*cb.z + xb.w*cb.w;
                    #pragma unroll
                    for (int m = 1; m < 64; m <<= 1) d += __shfl_xor(d, m, 64);
                    if (lane == 0) {
                        int lc2 = gcol & 255;
                        float sca = csq[gcol] - 2.f * d;
                        if (l == 1) sca += 2.f * G01[(size_t)isel[0][trow] * NK + lc2];
                        if (l == 2) sca += 2.f * (G02[(size_t)isel[0][trow] * NK + lc2] +
                                                  G12[(size_t)isel[1][trow] * NK + lc2]);
                        taskS[ti] = sca;
                    }
                }
            }
        }
        __syncthreads();                               // b4

        if (tid < 32) {
            int best = iseltmp[tid];
            if (ccnt[tid] >= 2) {
                float bvv = 3.4e38f; int bii = 0x7fffffff;
                int nt = ntask < 256 ? ntask : 256;
                for (int t = 0; t < nt; ++t) {
                    int rc = taskRC[t];
                    if ((rc >> 10) == tid) {
                        float s = taskS[t]; int c = rc & 1023;
                        if (s < bvv || (s == bvv && c < bii)) { bvv = s; bii = c; }
                    }
                }
                best = bii;
            }
            isel[l][tid] = best & 255;
        }
        __syncthreads();                               // b5
    }

    // ---- outputs ----
    if (tid < TM * 3) {
        int r = tid / 3, l = tid % 3;
        out[(size_t)(row0 + r) * 3 + l] = (float)isel[l][r];
    }
    float* rec = out + (size_t)ROWS * 3;
    #pragma unroll
    for (int q = 0; q < 8; ++q) {
        int idx = tid + 512 * q;          // 0..4095
        int r   = idx >> 7;               // 0..31
        int d4  = (idx & 127) * 4;
        float4 v0 = *reinterpret_cast<const float4*>(C + ((size_t)(  0 + isel[0][r])) * ND + d4);
        float4 v1 = *reinterpret_cast<const float4*>(C + ((size_t)(256 + isel[1][r])) * ND + d4);
        float4 v2 = *reinterpret_cast<const float4*>(C + ((size_t)(512 + isel[2][r])) * ND + d4);
        float4 o;
        o.x = v0.x + v1.x + v2.x;
        o.y = v0.y + v1.y + v2.y;
        o.z = v0.z + v1.z + v2.z;
        o.w = v0.w + v1.w + v2.w;
        *reinterpret_cast<float4*>(rec + (size_t)(row0 + r) * ND + d4) = o;
    }
}

// ---------------------------------------------------------------------------
extern "C" void kernel_launch(void* const* d_in, const int* in_sizes, int n_in,
                              void* d_out, int out_size, void* d_ws, size_t ws_size,
                              hipStream_t stream) {
    const float* X  = (const float*)d_in[0];   // [128,1024,512]
    const float* C  = (const float*)d_in[1];   // [3,256,512]
    float* ws  = (float*)d_ws;
    u16*   wsu = (u16*)d_ws;
    float* out = (float*)d_out;

    hipLaunchKernelGGL(prep_csq,    dim3(192),       dim3(256), 0, stream, C, ws);
    hipLaunchKernelGGL(prep_b,      dim3(192),       dim3(256), 0, stream, C, wsu);
    hipLaunchKernelGGL(gram_kernel, dim3(768),       dim3(256), 0, stream, C, ws);
    hipLaunchKernelGGL(rq_fused,    dim3(ROWS / TM), dim3(512), 0, stream,
                       X, C, ws, wsu, out);
}